// Round 10
// baseline (241.084 us; speedup 1.0000x reference)
//
#include <hip/hip_runtime.h>
#include <hip/hip_bf16.h>
#include <math.h>

#define N_PTS 1024
#define BT    128
typedef unsigned int u32;
typedef __attribute__((ext_vector_type(8))) short short8_t;   // 8 bf16 (4 VGPRs)
typedef __attribute__((ext_vector_type(4))) float f32x4;      // MFMA acc

__device__ __forceinline__ float bfi(u32 bits16) {
    union { u32 u; float f; } v; v.u = bits16 << 16; return v.f;
}
__device__ __forceinline__ unsigned short f2bf(float f) {     // RNE f32->bf16
    union { float f; u32 u; } v; v.f = f;
    return (unsigned short)((v.u + 0x7FFFu + ((v.u >> 16) & 1u)) >> 16);
}
__device__ __forceinline__ u32 pkbf(float a, float b) {       // pack 2 bf16 (RNE)
    union { __hip_bfloat162 b2; u32 u; } cv;
    cv.b2 = __float22bfloat162_rn(make_float2(a, b));
    return cv.u;
}
__device__ __forceinline__ float ldf(const void* p, int i, bool bf) {
    return bf ? bfi(((const unsigned short*)p)[i]) : ((const float*)p)[i];
}
__device__ __forceinline__ float2 ldp(const void* pbase, int j, bool bf) {
    if (bf) {
        u32 w = ((const u32*)pbase)[j];
        return make_float2(bfi(w & 0xFFFFu), bfi(w >> 16));
    }
    return ((const float2*)pbase)[j];
}
__device__ __forceinline__ bool detect_bf16(const void* pts, int tid, int* s_flag) {
    if (tid < 64) {
        u32 w = ((const u32*)pts)[tid];
        float v = bfi(w & 0xFFFFu);
        bool ok = (v >= 0.0f) && (v <= 1.0f);
        unsigned long long m = __ballot(ok);
        if (tid == 0) *s_flag = (m == 0xFFFFFFFFFFFFFFFFull) ? 1 : 0;
    }
    __syncthreads();
    return *s_flag != 0;
}
__device__ __forceinline__ bool is_nb(float px, float py, float qx, float qy) {
    float dx = px - qx, dy = py - qy;
    // ref: sqrt_rn(rn(rn(dx*dx)+rn(dy*dy))) < 0.3f  <=>  d2 < 0.09f (ulp-exact)
    float d2 = __fadd_rn(__fmul_rn(dx, dx), __fmul_rn(dy, dy));
    return d2 < 0.09f;
}
__device__ __forceinline__ const void* pts_base(const void* pts, int bt, bool bf) {
    return bf ? (const void*)((const unsigned short*)pts + (size_t)bt * N_PTS * 2)
              : (const void*)((const float*)pts + (size_t)bt * N_PTS * 2);
}
// async global->LDS, 16B per lane (lands at lds_base + lane*16) [m97 pattern]
__device__ __forceinline__ void gload16(const u32* g, u32* l) {
    __builtin_amdgcn_global_load_lds((const __attribute__((address_space(1))) u32*)g,
                                     (__attribute__((address_space(3))) u32*)l, 16, 0, 0);
}
// wave-uniform broadcast of lane `i` (compile-time) via v_readlane (VALU, not DS pipe)
__device__ __forceinline__ float rdlane(float v, int i) {
    return __int_as_float(__builtin_amdgcn_readlane(__float_as_int(v), i));
}
__device__ __forceinline__ float sigm(float x) {              // safe: exp->inf => 0
    return __fdividef(1.0f, 1.0f + __expf(-x));
}
__device__ __forceinline__ float tanh_f(float x) {            // 2*sigm(2x)-1, overflow-safe
    return fmaf(2.0f, __fdividef(1.0f, 1.0f + __expf(-2.0f * x)), -1.0f);
}

// K1: pair sweep -> adjacency bitmask bm[bt][chunk(32)][row(1024)] + cnt->dinv. Zeros gsum.
__global__ __launch_bounds__(256) void k1_bm(const void* __restrict__ pts,
                                             float* __restrict__ dinv,
                                             float* __restrict__ gsum,
                                             u32* __restrict__ bm) {
    int blk = blockIdx.x, tid = threadIdx.x;
    int bt = blk >> 2, q = blk & 3;
    __shared__ float2 sp[N_PTS];
    __shared__ int s_flag;
    bool bf = detect_bf16(pts, tid, &s_flag);
    const void* pb = pts_base(pts, bt, bf);
    for (int j = tid; j < N_PTS; j += 256) sp[j] = ldp(pb, j, bf);
    if (blk < 32) gsum[blk * 256 + tid] = 0.0f;
    __syncthreads();
    int i = q * 256 + tid;
    float px = sp[i].x, py = sp[i].y;
    const float4* sp4 = (const float4*)sp;
    u32* bmrow = bm + (size_t)bt * 32768 + i;
    int cnt = 0;
    for (int c = 0; c < 32; c++) {
        u32 m = 0;
#pragma unroll
        for (int h = 0; h < 8; h++) {
            float4 s01 = sp4[c * 16 + 2 * h], s23 = sp4[c * 16 + 2 * h + 1];
            if (is_nb(px, py, s01.x, s01.y)) m |= 1u << (4 * h);
            if (is_nb(px, py, s01.z, s01.w)) m |= 1u << (4 * h + 1);
            if (is_nb(px, py, s23.x, s23.y)) m |= 1u << (4 * h + 2);
            if (is_nb(px, py, s23.z, s23.w)) m |= 1u << (4 * h + 3);
        }
        bmrow[c * 1024] = m;
        cnt += __popc(m);
    }
    dinv[bt * N_PTS + i] = 1.0f / sqrtf((float)cnt);
}

// K3a: layer-1 aggregation via MFMA. (An@pts)@W1^T == An@(pts@W1^T).
// R9 BUG FIX: dumpX stride was 44 dw/ch but 256 rows need 128 dw/ch -> write race
// clobbered x1v tiles (absmax 8.5e-3). Stride now 132 (=128+4 pad; 64*132=8448
// dwords exactly fits the dead bmL region).
__global__ __launch_bounds__(256) void k3a_x1v(const void* __restrict__ pts,
                                               const void* __restrict__ W1,
                                               const void* __restrict__ b1,
                                               const float* __restrict__ dinv,
                                               const u32* __restrict__ bm,
                                               u32* __restrict__ x1vB) {
    // dwords: sud f2[1024] [0,2048) | bmL [2048,10496) [row][33] | sdi [10496,10752)
    // b1L [10752,10816) | W1L [10816,10944). dumpX[ch(64)][132] overlays bmL post-loop.
    __shared__ u32 pool[10944];
    __shared__ int s_flag;
    float* poolf = (float*)pool;
    float2* sud = (float2*)pool;
    u32* bmL = pool + 2048;
    float* sdiL = poolf + 10496;
    float* b1L = poolf + 10752;
    float* W1L = poolf + 10816;
    int tid = threadIdx.x, lane = tid & 63, w = tid >> 6;
    int l15 = lane & 15, quad = lane >> 4;
    int blk = blockIdx.x, bt = blk & 127, rowblk = blk >> 7;
    int rowbase = rowblk * 256;
    bool bf = detect_bf16(pts, tid, &s_flag);
    const void* pb = pts_base(pts, bt, bf);
    for (int j = tid; j < N_PTS; j += 256) {
        float2 p = ldp(pb, j, bf);
        float d = dinv[bt * N_PTS + j];
        sud[j] = make_float2(d * p.x, d * p.y);
    }
    sdiL[tid] = dinv[bt * N_PTS + rowbase + tid];
    for (int idx = tid; idx < 8192; idx += 256) {
        int c = idx >> 8, r = idx & 255;
        bmL[r * 33 + c] = bm[(size_t)bt * 32768 + c * 1024 + rowbase + r];
    }
    if (tid < 128) W1L[tid] = ldf(W1, tid, bf);
    if (tid < 64)  b1L[tid] = ldf(b1, tid, bf);
    __syncthreads();

    float w0v[4], w1v[4], b1v[4];
#pragma unroll
    for (int nb = 0; nb < 4; nb++) {
        int ch = nb * 16 + l15;
        w0v[nb] = W1L[2 * ch]; w1v[nb] = W1L[2 * ch + 1]; b1v[nb] = b1L[ch];
    }
    f32x4 acc[4][4];
#pragma unroll
    for (int rf = 0; rf < 4; rf++)
#pragma unroll
        for (int nb = 0; nb < 4; nb++)
#pragma unroll
            for (int r = 0; r < 4; r++) acc[rf][nb][r] = 0.0f;

    for (int ks = 0; ks < 32; ks++) {
        const float4* u4 = (const float4*)(sud + ks * 32 + quad * 8);
        float4 U0 = u4[0], U1 = u4[1], U2 = u4[2], U3 = u4[3];
        float pxd[8] = {U0.x, U0.z, U1.x, U1.z, U2.x, U2.z, U3.x, U3.z};
        float pyd[8] = {U0.y, U0.w, U1.y, U1.w, U2.y, U2.w, U3.y, U3.w};
        short8_t bz[4];
#pragma unroll
        for (int nb = 0; nb < 4; nb++) {
            union { short8_t v; u32 d[4]; } cv;
#pragma unroll
            for (int p = 0; p < 4; p++) {
                float z0 = fmaf(pxd[2 * p],     w0v[nb], pyd[2 * p]     * w1v[nb]);
                float z1 = fmaf(pxd[2 * p + 1], w0v[nb], pyd[2 * p + 1] * w1v[nb]);
                cv.d[p] = pkbf(z0, z1);
            }
            bz[nb] = cv.v;
        }
#pragma unroll
        for (int rf = 0; rf < 4; rf++) {
            u32 word = bmL[(w * 64 + rf * 16 + l15) * 33 + ks];
            u32 by = (word >> (quad * 8)) & 0xFFu;
            short8_t av;
#pragma unroll
            for (int i2 = 0; i2 < 8; i2++)
                av[i2] = (by & (1u << i2)) ? (short)0x3F80 : (short)0;
#pragma unroll
            for (int nb = 0; nb < 4; nb++)
                acc[rf][nb] = __builtin_amdgcn_mfma_f32_16x16x32_bf16(av, bz[nb], acc[rf][nb], 0, 0, 0);
        }
    }
    __syncthreads();   // bmL dead -> dumpX
    u32* dumpX = pool + 2048;   // [ch][132 dw], rows packed in pairs
#pragma unroll
    for (int rf = 0; rf < 4; rf++) {
        float4 dv = *(const float4*)(sdiL + w * 64 + rf * 16 + quad * 4);
        float dva[4] = {dv.x, dv.y, dv.z, dv.w};
#pragma unroll
        for (int nb = 0; nb < 4; nb++) {
            int ch = nb * 16 + l15;
            float xo[4];
#pragma unroll
            for (int r = 0; r < 4; r++) {
                float tq = fmaf(dva[r], acc[rf][nb][r], b1v[nb]);
                xo[r] = dva[r] * fmaxf(tq, 0.0f);
            }
            u32 dbase = (u32)(ch * 132 + w * 32 + rf * 8 + quad * 2);
            *(uint2*)(dumpX + dbase) = make_uint2(pkbf(xo[0], xo[1]), pkbf(xo[2], xo[3]));
        }
    }
    __syncthreads();
    int ch = tid >> 2, seg = tid & 3;
    u32* gbase = x1vB + ((size_t)(bt * 16 + rowblk * 4) * 64) * 36;
#pragma unroll
    for (int t4 = 0; t4 < 4; t4++) {
        const uint4* src = (const uint4*)(dumpX + ch * 132 + t4 * 32 + seg * 8);
        uint4 v0 = src[0], v1 = src[1];
        u32* dst = gbase + ((size_t)(t4 * 64 + ch)) * 36 + seg * 8;
        *(uint4*)dst = v0; *(uint4*)(dst + 4) = v1;
    }
}

// K3b: D^T = x1v^T @ A (A symmetric 0/1 from bitmask, in-register B-frags);
// epilogue W2 @ (di*D^T) via 2nd MFMA; relu+rowsum -> atomic gsum. (unchanged)
__global__ __launch_bounds__(256) void k3_mfma(const void* __restrict__ pts,
                                               const void* __restrict__ W2,
                                               const void* __restrict__ b2,
                                               const float* __restrict__ dinv,
                                               const u32* __restrict__ bm,
                                               const u32* __restrict__ x1vB,
                                               float* __restrict__ gsum) {
    __shared__ u32 pool[15424];
    __shared__ int s_flag;
    float* poolf = (float*)pool;
    int tid = threadIdx.x, lane = tid & 63, w = tid >> 6;
    int l15 = lane & 15, quad = lane >> 4;
    int blk = blockIdx.x, bt = blk & 127, rowblk = blk >> 7;
    bool bf = detect_bf16(pts, tid, &s_flag);

    const u32* xg = x1vB + (size_t)bt * 36864;
    for (int it = w; it < 9; it += 4)
        gload16(xg + it * 256 + lane * 4, pool + 8192 + it * 256 + lane * 4);

    const u32* bg_ = bm + (size_t)bt * 32768 + rowblk * 256;
    for (int idx = tid; idx < 8192; idx += 256) {
        int c = idx >> 8, r = idx & 255;
        pool[idx] = bg_[c * 1024 + r];
    }
    unsigned short* W2B = (unsigned short*)(pool + 12800);
    for (int idx = tid; idx < 4096; idx += 256) {
        int o = idx >> 6, c = idx & 63;
        W2B[o * 72 + c] = f2bf(ldf(W2, idx, bf));
    }
    if (tid < 256) poolf[15104 + tid] = dinv[bt * N_PTS + rowblk * 256 + tid];
    if (tid < 64)  poolf[15360 + tid] = ldf(b2, tid, bf);

    f32x4 acc[4][4];
#pragma unroll
    for (int rf = 0; rf < 4; rf++)
#pragma unroll
        for (int nb = 0; nb < 4; nb++)
#pragma unroll
            for (int r = 0; r < 4; r++) acc[rf][nb][r] = 0.0f;

    for (int t = 0; t < 16; t++) {
        __syncthreads();
        if (t + 1 < 16) {
            u32* dst = pool + ((t & 1) ? 8192 : 10496);
            const u32* src = xg + (t + 1) * 2304;
            for (int it = w; it < 9; it += 4)
                gload16(src + it * 256 + lane * 4, dst + it * 256 + lane * 4);
        }
        const unsigned short* xf = (const unsigned short*)(pool + ((t & 1) ? 10496 : 8192));
#pragma unroll
        for (int ks = 0; ks < 2; ks++) {
            short8_t bq[4];
#pragma unroll
            for (int rf = 0; rf < 4; rf++) {
                u32 mw = pool[(2 * t + ks) * 256 + w * 64 + rf * 16 + l15];
                u32 by = (mw >> (quad * 8)) & 0xFFu;
                short8_t v;
#pragma unroll
                for (int i2 = 0; i2 < 8; i2++)
                    v[i2] = (by & (1u << i2)) ? (short)0x3F80 : (short)0;
                bq[rf] = v;
            }
#pragma unroll
            for (int nb = 0; nb < 4; nb++) {
                short8_t af = *(const short8_t*)(xf + (nb * 16 + l15) * 72 + ks * 32 + quad * 8);
#pragma unroll
                for (int rf = 0; rf < 4; rf++)
                    acc[rf][nb] = __builtin_amdgcn_mfma_f32_16x16x32_bf16(af, bq[rf], acc[rf][nb], 0, 0, 0);
            }
        }
    }
    __syncthreads();

    u32* dump = pool;
#pragma unroll
    for (int rf = 0; rf < 4; rf++) {
        int rn = w * 64 + rf * 16 + l15;
        float di = poolf[15104 + rn];
#pragma unroll
        for (int nb = 0; nb < 4; nb++) {
            u32 lo = (u32)f2bf(acc[rf][nb][0] * di) | ((u32)f2bf(acc[rf][nb][1] * di) << 16);
            u32 hi = (u32)f2bf(acc[rf][nb][2] * di) | ((u32)f2bf(acc[rf][nb][3] * di) << 16);
            u32* dst = dump + rn * 36 + nb * 8 + quad * 2;
            dst[0] = lo; dst[1] = hi;
        }
    }
    __syncthreads();
    f32x4 xacc[4][4];
#pragma unroll
    for (int ob = 0; ob < 4; ob++)
#pragma unroll
        for (int rf = 0; rf < 4; rf++)
#pragma unroll
            for (int r = 0; r < 4; r++) xacc[ob][rf][r] = 0.0f;
#pragma unroll
    for (int ks2 = 0; ks2 < 2; ks2++) {
        short8_t b2f[4];
#pragma unroll
        for (int rf = 0; rf < 4; rf++)
            b2f[rf] = *(const short8_t*)((const unsigned short*)dump +
                        (w * 64 + rf * 16 + l15) * 72 + ks2 * 32 + quad * 8);
#pragma unroll
        for (int ob = 0; ob < 4; ob++) {
            short8_t a2 = *(const short8_t*)(W2B + (ob * 16 + l15) * 72 + ks2 * 32 + quad * 8);
#pragma unroll
            for (int rf = 0; rf < 4; rf++)
                xacc[ob][rf] = __builtin_amdgcn_mfma_f32_16x16x32_bf16(a2, b2f[rf], xacc[ob][rf], 0, 0, 0);
        }
    }
#pragma unroll
    for (int ob = 0; ob < 4; ob++) {
#pragma unroll
        for (int r = 0; r < 4; r++) {
            int o = ob * 16 + quad * 4 + r;
            float bb = poolf[15360 + o];
            float s = 0.0f;
#pragma unroll
            for (int rf = 0; rf < 4; rf++) s += fmaxf(xacc[ob][rf][r] + bb, 0.0f);
            s += __shfl_down(s, 8, 16);
            s += __shfl_down(s, 4, 16);
            s += __shfl_down(s, 2, 16);
            s += __shfl_down(s, 1, 16);
            if (l15 == 0) atomicAdd(&gsum[bt * 64 + o], s);
        }
    }
}

// K4 v4: h lives in registers (every wave redundantly computes its half's gates),
// ONE barrier/iter (s_part parity-dbuf), fast transcendentals (__expf/__fdividef).
__global__ __launch_bounds__(768, 1) void k4_all(const void* __restrict__ pts,
                                                 const void* __restrict__ Wg,
                                                 const void* __restrict__ bg,
                                                 const void* __restrict__ Wih,
                                                 const void* __restrict__ Whh,
                                                 const void* __restrict__ bih,
                                                 const void* __restrict__ bhh,
                                                 const void* __restrict__ Wf,
                                                 const void* __restrict__ bf_,
                                                 const float* __restrict__ gsum,
                                                 float* __restrict__ out) {
    int b = blockIdx.x, tid = threadIdx.x;
    __shared__ float s_gir[4096];      // [t][c] gate inputs (stride-1, conflict-free)
    __shared__ float s_giz[4096];
    __shared__ float s_gin[4096];
    __shared__ float sWgT[64 * 65];
    __shared__ float s_gm[2048];
    __shared__ float s_x[2048];
    __shared__ float s_pt[2 * 6 * 128]; // parity-dbuf partials [buf][slot][c]
    __shared__ int s_flag;
    bool bf = detect_bf16(pts, tid, &s_flag);
    for (int idx = tid; idx < 4096; idx += 768) {
        int o = idx >> 6, k = idx & 63;
        sWgT[k * 65 + o] = ldf(Wg, idx, bf);
    }
    for (int idx = tid; idx < 2048; idx += 768)
        s_gm[idx] = gsum[(size_t)b * 2048 + idx] * (1.0f / 1024.0f);
    __syncthreads();
    for (int idx = tid; idx < 2048; idx += 768) {
        int t = idx >> 6, c = idx & 63;
        float s0 = ldf(bg, c, bf), s1 = 0.f, s2 = 0.f, s3 = 0.f;
        const float* gm = s_gm + t * 64;
#pragma unroll
        for (int k = 0; k < 64; k += 4) {
            s0 = fmaf(sWgT[k * 65 + c],       gm[k],     s0);
            s1 = fmaf(sWgT[(k + 1) * 65 + c], gm[k + 1], s1);
            s2 = fmaf(sWgT[(k + 2) * 65 + c], gm[k + 2], s2);
            s3 = fmaf(sWgT[(k + 3) * 65 + c], gm[k + 3], s3);
        }
        s_x[idx] = (s0 + s1) + (s2 + s3);
    }
    __syncthreads();
    int hi = (tid >= 384) ? 1 : 0;      // wave-uniform
    int r = tid - hi * 384;             // 0..383
    int g = r >> 7;                      // gate 0=r,1=z,2=n (wave-uniform)
    int cpart = r & 127;
    int lane = tid & 63;
    int wv = tid >> 6;
    float* gdst = (g == 0) ? s_gir : (g == 1) ? s_giz : s_gin;
    // gi[t][r] for t ≡ hi (mod 2); Wih row r in regs; x[t] broadcast via readlane
    {
        float wvr[64];
        if (bf) {
#pragma unroll
            for (int k = 0; k < 64; k++) wvr[k] = bfi(((const unsigned short*)Wih)[r * 64 + k]);
        } else {
            const float4* wr = (const float4*)Wih + r * 16;
#pragma unroll
            for (int qq = 0; qq < 16; qq++) {
                float4 v = wr[qq];
                wvr[4*qq] = v.x; wvr[4*qq+1] = v.y; wvr[4*qq+2] = v.z; wvr[4*qq+3] = v.w;
            }
        }
        float br = ldf(bih, r, bf);
        for (int t = hi; t < 32; t += 2) {
            float xv = s_x[t * 64 + lane];
            float s0 = br, s1 = 0.f, s2 = 0.f, s3 = 0.f;
#pragma unroll
            for (int k = 0; k < 64; k += 4) {
                s0 = fmaf(wvr[k],     rdlane(xv, k),     s0);
                s1 = fmaf(wvr[k + 1], rdlane(xv, k + 1), s1);
                s2 = fmaf(wvr[k + 2], rdlane(xv, k + 2), s2);
                s3 = fmaf(wvr[k + 3], rdlane(xv, k + 3), s3);
            }
            gdst[t * 128 + cpart] = (s0 + s1) + (s2 + s3);
        }
    }
    // Whh half-row in regs
    float wh2[64];
    {
        int koff = hi * 64;
        if (bf) {
#pragma unroll
            for (int k = 0; k < 64; k++)
                wh2[k] = bfi(((const unsigned short*)Whh)[r * 128 + koff + k]);
        } else {
            const float4* wr = (const float4*)Whh + (r * 128 + koff) / 4;
#pragma unroll
            for (int qq = 0; qq < 16; qq++) {
                float4 v = wr[qq];
                wh2[4*qq] = v.x; wh2[4*qq+1] = v.y; wh2[4*qq+2] = v.z; wh2[4*qq+3] = v.w;
            }
        }
    }
    float bhr = hi ? 0.0f : ldf(bhh, r, bf);
    int slot = g * 2 + hi;               // 0..5, wave-uniform
    int cg = hi * 64 + lane;             // this wave's gate channel
    float h_self = 0.0f, hsum = 0.0f;
    __syncthreads();

    for (int t = 0; t < 32; t++) {
        // matvec partial: h broadcast from own registers via readlane
        float s0 = bhr, s1 = 0.f, s2 = 0.f, s3 = 0.f;
#pragma unroll
        for (int k = 0; k < 64; k += 4) {
            s0 = fmaf(wh2[k],     rdlane(h_self, k),     s0);
            s1 = fmaf(wh2[k + 1], rdlane(h_self, k + 1), s1);
            s2 = fmaf(wh2[k + 2], rdlane(h_self, k + 2), s2);
            s3 = fmaf(wh2[k + 3], rdlane(h_self, k + 3), s3);
        }
        float* buf = s_pt + (t & 1) * 768;
        buf[slot * 128 + cpart] = (s0 + s1) + (s2 + s3);
        __syncthreads();
        // gates (redundant per wave for its own half -> h stays in registers)
        float gr = s_gir[t * 128 + cg] + buf[0 * 128 + cg] + buf[1 * 128 + cg];
        float gz = s_giz[t * 128 + cg] + buf[2 * 128 + cg] + buf[3 * 128 + cg];
        float hn = buf[4 * 128 + cg] + buf[5 * 128 + cg];
        float rr = sigm(gr);
        float zz = sigm(gz);
        float gn = fmaf(rr, hn, s_gin[t * 128 + cg]);
        float n  = tanh_f(gn);
        float hnew = fmaf(zz, h_self - n, n);
        h_self = hnew; hsum += hnew;
        // WAR safe: next iter writes the other parity buffer
    }
    float* sfin = s_gm;   // reuse (dead)
    if (wv == 0) sfin[lane] = hsum;
    if (wv == 6) sfin[64 + lane] = hsum;
    __syncthreads();
    if (tid < 128) {
        float hm = sfin[tid] * (1.0f / 32.0f);
        sfin[256 + tid] = ldf(Wf, tid, bf) * hm;
        sfin[384 + tid] = ldf(Wf, 128 + tid, bf) * hm;
    }
    __syncthreads();
    if (tid < 2) {
        float s = ldf(bf_, tid, bf);
        for (int k = 0; k < 128; k++) s += sfin[256 + tid * 128 + k];
        out[b * 2 + tid] = s;   // f32 output (verified R4)
    }
}

extern "C" void kernel_launch(void* const* d_in, const int* in_sizes, int n_in,
                              void* d_out, int out_size, void* d_ws, size_t ws_size,
                              hipStream_t stream) {
    const void* pts = d_in[0];
    const void* W1  = d_in[1];
    const void* b1  = d_in[2];
    const void* W2  = d_in[3];
    const void* b2  = d_in[4];
    const void* Wg  = d_in[5];
    const void* bg  = d_in[6];
    const void* Wih = d_in[7];
    const void* Whh = d_in[8];
    const void* bih = d_in[9];
    const void* bhh = d_in[10];
    const void* Wf  = d_in[11];
    const void* bf_ = d_in[12];

    // ws: dinv 512K | gsum 32K | bm 16M | x1vB 18M  (~34.5 MB)
    float* dinv = (float*)d_ws;
    float* gsum = dinv + (size_t)BT * N_PTS;
    u32*   bm   = (u32*)(gsum + BT * 64);
    u32*   x1vB = bm + (size_t)BT * 32768;

    k1_bm  <<<512, 256, 0, stream>>>(pts, dinv, gsum, bm);
    k3a_x1v<<<512, 256, 0, stream>>>(pts, W1, b1, dinv, bm, x1vB);
    k3_mfma<<<512, 256, 0, stream>>>(pts, W2, b2, dinv, bm, x1vB, gsum);
    k4_all <<<4, 768, 0, stream>>>(pts, Wg, bg, Wih, Whh, bih, bhh, Wf, bf_,
                                   gsum, (float*)d_out);
}

// Round 12
// 240.815 us; speedup vs baseline: 1.0011x; 1.0011x over previous
//
#include <hip/hip_runtime.h>
#include <hip/hip_bf16.h>
#include <math.h>

#define N_PTS 1024
#define BT    128
typedef unsigned int u32;
typedef __attribute__((ext_vector_type(8))) short short8_t;   // 8 bf16 (4 VGPRs)
typedef __attribute__((ext_vector_type(4))) float f32x4;      // MFMA acc
typedef __fp16 fp16x2 __attribute__((ext_vector_type(2)));    // cvt_pkrtz result type
typedef _Float16 f16x2 __attribute__((ext_vector_type(2)));   // fdot2 operand type

#if defined(__has_builtin)
#if __has_builtin(__builtin_amdgcn_fdot2)
#define HAVE_FDOT2 1
#endif
#endif
#ifndef HAVE_FDOT2
#define HAVE_FDOT2 0
#endif

__device__ __forceinline__ float bfi(u32 bits16) {
    union { u32 u; float f; } v; v.u = bits16 << 16; return v.f;
}
__device__ __forceinline__ unsigned short f2bf(float f) {     // RNE f32->bf16
    union { float f; u32 u; } v; v.f = f;
    return (unsigned short)((v.u + 0x7FFFu + ((v.u >> 16) & 1u)) >> 16);
}
__device__ __forceinline__ u32 pkbf(float a, float b) {       // pack 2 bf16 (RNE)
    union { __hip_bfloat162 b2; u32 u; } cv;
    cv.b2 = __float22bfloat162_rn(make_float2(a, b));
    return cv.u;
}
__device__ __forceinline__ u32 pkh(float a, float b) {        // pack 2 f16 (RTZ)
    union { fp16x2 h; u32 u; } c; c.h = __builtin_amdgcn_cvt_pkrtz(a, b); return c.u;
}
__device__ __forceinline__ unsigned short f16b(float v) {
    union { fp16x2 h; unsigned short s[2]; } c;
    c.h = __builtin_amdgcn_cvt_pkrtz(v, 0.0f);
    return c.s[0];
}
#if HAVE_FDOT2
__device__ __forceinline__ float fdot2h(u32 a, u32 b, float c) {
    union { u32 u; f16x2 h; } A, B; A.u = a; B.u = b;
    return __builtin_amdgcn_fdot2(A.h, B.h, c, false);
}
#else
__device__ __forceinline__ float fdot2h(u32 a, u32 b, float c) {
    union { u32 u; _Float16 h[2]; } A, B; A.u = a; B.u = b;
    return fmaf((float)A.h[0], (float)B.h[0], fmaf((float)A.h[1], (float)B.h[1], c));
}
#endif
__device__ __forceinline__ float ldf(const void* p, int i, bool bf) {
    return bf ? bfi(((const unsigned short*)p)[i]) : ((const float*)p)[i];
}
__device__ __forceinline__ float2 ldp(const void* pbase, int j, bool bf) {
    if (bf) {
        u32 w = ((const u32*)pbase)[j];
        return make_float2(bfi(w & 0xFFFFu), bfi(w >> 16));
    }
    return ((const float2*)pbase)[j];
}
__device__ __forceinline__ bool detect_bf16(const void* pts, int tid, int* s_flag) {
    if (tid < 64) {
        u32 w = ((const u32*)pts)[tid];
        float v = bfi(w & 0xFFFFu);
        bool ok = (v >= 0.0f) && (v <= 1.0f);
        unsigned long long m = __ballot(ok);
        if (tid == 0) *s_flag = (m == 0xFFFFFFFFFFFFFFFFull) ? 1 : 0;
    }
    __syncthreads();
    return *s_flag != 0;
}
__device__ __forceinline__ bool is_nb(float px, float py, float qx, float qy) {
    float dx = px - qx, dy = py - qy;
    // ref: sqrt_rn(rn(rn(dx*dx)+rn(dy*dy))) < 0.3f  <=>  d2 < 0.09f (ulp-exact)
    float d2 = __fadd_rn(__fmul_rn(dx, dx), __fmul_rn(dy, dy));
    return d2 < 0.09f;
}
__device__ __forceinline__ const void* pts_base(const void* pts, int bt, bool bf) {
    return bf ? (const void*)((const unsigned short*)pts + (size_t)bt * N_PTS * 2)
              : (const void*)((const float*)pts + (size_t)bt * N_PTS * 2);
}
// async global->LDS, 16B per lane (lands at lds_base + lane*16) [m97 pattern]
__device__ __forceinline__ void gload16(const u32* g, u32* l) {
    __builtin_amdgcn_global_load_lds((const __attribute__((address_space(1))) u32*)g,
                                     (__attribute__((address_space(3))) u32*)l, 16, 0, 0);
}
// wave-uniform broadcast of lane `i` (compile-time) via v_readlane (VALU, not DS pipe)
__device__ __forceinline__ u32 rdlaneu(u32 v, int i) {
    return (u32)__builtin_amdgcn_readlane((int)v, i);
}
__device__ __forceinline__ float sigm(float x) {              // safe: exp->inf => 0
    return __fdividef(1.0f, 1.0f + __expf(-x));
}
__device__ __forceinline__ float tanh_f(float x) {            // 2*sigm(2x)-1, overflow-safe
    return fmaf(2.0f, __fdividef(1.0f, 1.0f + __expf(-2.0f * x)), -1.0f);
}

// K1: pair sweep -> adjacency bitmask bm[bt][chunk(32)][row(1024)] + cnt->dinv. Zeros gsum.
__global__ __launch_bounds__(256) void k1_bm(const void* __restrict__ pts,
                                             float* __restrict__ dinv,
                                             float* __restrict__ gsum,
                                             u32* __restrict__ bm) {
    int blk = blockIdx.x, tid = threadIdx.x;
    int bt = blk >> 2, q = blk & 3;
    __shared__ float2 sp[N_PTS];
    __shared__ int s_flag;
    bool bf = detect_bf16(pts, tid, &s_flag);
    const void* pb = pts_base(pts, bt, bf);
    for (int j = tid; j < N_PTS; j += 256) sp[j] = ldp(pb, j, bf);
    if (blk < 32) gsum[blk * 256 + tid] = 0.0f;
    __syncthreads();
    int i = q * 256 + tid;
    float px = sp[i].x, py = sp[i].y;
    const float4* sp4 = (const float4*)sp;
    u32* bmrow = bm + (size_t)bt * 32768 + i;
    int cnt = 0;
    for (int c = 0; c < 32; c++) {
        u32 m = 0;
#pragma unroll
        for (int h = 0; h < 8; h++) {
            float4 s01 = sp4[c * 16 + 2 * h], s23 = sp4[c * 16 + 2 * h + 1];
            if (is_nb(px, py, s01.x, s01.y)) m |= 1u << (4 * h);
            if (is_nb(px, py, s01.z, s01.w)) m |= 1u << (4 * h + 1);
            if (is_nb(px, py, s23.x, s23.y)) m |= 1u << (4 * h + 2);
            if (is_nb(px, py, s23.z, s23.w)) m |= 1u << (4 * h + 3);
        }
        bmrow[c * 1024] = m;
        cnt += __popc(m);
    }
    dinv[bt * N_PTS + i] = 1.0f / sqrtf((float)cnt);
}

// K3a: layer-1 aggregation via MFMA. (An@pts)@W1^T == An@(pts@W1^T). (verified R10)
__global__ __launch_bounds__(256) void k3a_x1v(const void* __restrict__ pts,
                                               const void* __restrict__ W1,
                                               const void* __restrict__ b1,
                                               const float* __restrict__ dinv,
                                               const u32* __restrict__ bm,
                                               u32* __restrict__ x1vB) {
    __shared__ u32 pool[10944];
    __shared__ int s_flag;
    float* poolf = (float*)pool;
    float2* sud = (float2*)pool;
    u32* bmL = pool + 2048;
    float* sdiL = poolf + 10496;
    float* b1L = poolf + 10752;
    float* W1L = poolf + 10816;
    int tid = threadIdx.x, lane = tid & 63, w = tid >> 6;
    int l15 = lane & 15, quad = lane >> 4;
    int blk = blockIdx.x, bt = blk & 127, rowblk = blk >> 7;
    int rowbase = rowblk * 256;
    bool bf = detect_bf16(pts, tid, &s_flag);
    const void* pb = pts_base(pts, bt, bf);
    for (int j = tid; j < N_PTS; j += 256) {
        float2 p = ldp(pb, j, bf);
        float d = dinv[bt * N_PTS + j];
        sud[j] = make_float2(d * p.x, d * p.y);
    }
    sdiL[tid] = dinv[bt * N_PTS + rowbase + tid];
    for (int idx = tid; idx < 8192; idx += 256) {
        int c = idx >> 8, r = idx & 255;
        bmL[r * 33 + c] = bm[(size_t)bt * 32768 + c * 1024 + rowbase + r];
    }
    if (tid < 128) W1L[tid] = ldf(W1, tid, bf);
    if (tid < 64)  b1L[tid] = ldf(b1, tid, bf);
    __syncthreads();

    float w0v[4], w1v[4], b1v[4];
#pragma unroll
    for (int nb = 0; nb < 4; nb++) {
        int ch = nb * 16 + l15;
        w0v[nb] = W1L[2 * ch]; w1v[nb] = W1L[2 * ch + 1]; b1v[nb] = b1L[ch];
    }
    f32x4 acc[4][4];
#pragma unroll
    for (int rf = 0; rf < 4; rf++)
#pragma unroll
        for (int nb = 0; nb < 4; nb++)
#pragma unroll
            for (int r = 0; r < 4; r++) acc[rf][nb][r] = 0.0f;

    for (int ks = 0; ks < 32; ks++) {
        const float4* u4 = (const float4*)(sud + ks * 32 + quad * 8);
        float4 U0 = u4[0], U1 = u4[1], U2 = u4[2], U3 = u4[3];
        float pxd[8] = {U0.x, U0.z, U1.x, U1.z, U2.x, U2.z, U3.x, U3.z};
        float pyd[8] = {U0.y, U0.w, U1.y, U1.w, U2.y, U2.w, U3.y, U3.w};
        short8_t bz[4];
#pragma unroll
        for (int nb = 0; nb < 4; nb++) {
            union { short8_t v; u32 d[4]; } cv;
#pragma unroll
            for (int p = 0; p < 4; p++) {
                float z0 = fmaf(pxd[2 * p],     w0v[nb], pyd[2 * p]     * w1v[nb]);
                float z1 = fmaf(pxd[2 * p + 1], w0v[nb], pyd[2 * p + 1] * w1v[nb]);
                cv.d[p] = pkbf(z0, z1);
            }
            bz[nb] = cv.v;
        }
#pragma unroll
        for (int rf = 0; rf < 4; rf++) {
            u32 word = bmL[(w * 64 + rf * 16 + l15) * 33 + ks];
            u32 by = (word >> (quad * 8)) & 0xFFu;
            short8_t av;
#pragma unroll
            for (int i2 = 0; i2 < 8; i2++)
                av[i2] = (by & (1u << i2)) ? (short)0x3F80 : (short)0;
#pragma unroll
            for (int nb = 0; nb < 4; nb++)
                acc[rf][nb] = __builtin_amdgcn_mfma_f32_16x16x32_bf16(av, bz[nb], acc[rf][nb], 0, 0, 0);
        }
    }
    __syncthreads();   // bmL dead -> dumpX
    u32* dumpX = pool + 2048;   // [ch][132 dw], rows packed in pairs
#pragma unroll
    for (int rf = 0; rf < 4; rf++) {
        float4 dv = *(const float4*)(sdiL + w * 64 + rf * 16 + quad * 4);
        float dva[4] = {dv.x, dv.y, dv.z, dv.w};
#pragma unroll
        for (int nb = 0; nb < 4; nb++) {
            int ch = nb * 16 + l15;
            float xo[4];
#pragma unroll
            for (int r = 0; r < 4; r++) {
                float tq = fmaf(dva[r], acc[rf][nb][r], b1v[nb]);
                xo[r] = dva[r] * fmaxf(tq, 0.0f);
            }
            u32 dbase = (u32)(ch * 132 + w * 32 + rf * 8 + quad * 2);
            *(uint2*)(dumpX + dbase) = make_uint2(pkbf(xo[0], xo[1]), pkbf(xo[2], xo[3]));
        }
    }
    __syncthreads();
    int ch = tid >> 2, seg = tid & 3;
    u32* gbase = x1vB + ((size_t)(bt * 16 + rowblk * 4) * 64) * 36;
#pragma unroll
    for (int t4 = 0; t4 < 4; t4++) {
        const uint4* src = (const uint4*)(dumpX + ch * 132 + t4 * 32 + seg * 8);
        uint4 v0 = src[0], v1 = src[1];
        u32* dst = gbase + ((size_t)(t4 * 64 + ch)) * 36 + seg * 8;
        *(uint4*)dst = v0; *(uint4*)(dst + 4) = v1;
    }
}

// K3b: D^T = x1v^T @ A; epilogue W2 @ (di*D^T) via 2nd MFMA. (unchanged, verified)
__global__ __launch_bounds__(256) void k3_mfma(const void* __restrict__ pts,
                                               const void* __restrict__ W2,
                                               const void* __restrict__ b2,
                                               const float* __restrict__ dinv,
                                               const u32* __restrict__ bm,
                                               const u32* __restrict__ x1vB,
                                               float* __restrict__ gsum) {
    __shared__ u32 pool[15424];
    __shared__ int s_flag;
    float* poolf = (float*)pool;
    int tid = threadIdx.x, lane = tid & 63, w = tid >> 6;
    int l15 = lane & 15, quad = lane >> 4;
    int blk = blockIdx.x, bt = blk & 127, rowblk = blk >> 7;
    bool bf = detect_bf16(pts, tid, &s_flag);

    const u32* xg = x1vB + (size_t)bt * 36864;
    for (int it = w; it < 9; it += 4)
        gload16(xg + it * 256 + lane * 4, pool + 8192 + it * 256 + lane * 4);

    const u32* bg_ = bm + (size_t)bt * 32768 + rowblk * 256;
    for (int idx = tid; idx < 8192; idx += 256) {
        int c = idx >> 8, r = idx & 255;
        pool[idx] = bg_[c * 1024 + r];
    }
    unsigned short* W2B = (unsigned short*)(pool + 12800);
    for (int idx = tid; idx < 4096; idx += 256) {
        int o = idx >> 6, c = idx & 63;
        W2B[o * 72 + c] = f2bf(ldf(W2, idx, bf));
    }
    if (tid < 256) poolf[15104 + tid] = dinv[bt * N_PTS + rowblk * 256 + tid];
    if (tid < 64)  poolf[15360 + tid] = ldf(b2, tid, bf);

    f32x4 acc[4][4];
#pragma unroll
    for (int rf = 0; rf < 4; rf++)
#pragma unroll
        for (int nb = 0; nb < 4; nb++)
#pragma unroll
            for (int r = 0; r < 4; r++) acc[rf][nb][r] = 0.0f;

    for (int t = 0; t < 16; t++) {
        __syncthreads();
        if (t + 1 < 16) {
            u32* dst = pool + ((t & 1) ? 8192 : 10496);
            const u32* src = xg + (t + 1) * 2304;
            for (int it = w; it < 9; it += 4)
                gload16(src + it * 256 + lane * 4, dst + it * 256 + lane * 4);
        }
        const unsigned short* xf = (const unsigned short*)(pool + ((t & 1) ? 10496 : 8192));
#pragma unroll
        for (int ks = 0; ks < 2; ks++) {
            short8_t bq[4];
#pragma unroll
            for (int rf = 0; rf < 4; rf++) {
                u32 mw = pool[(2 * t + ks) * 256 + w * 64 + rf * 16 + l15];
                u32 by = (mw >> (quad * 8)) & 0xFFu;
                short8_t v;
#pragma unroll
                for (int i2 = 0; i2 < 8; i2++)
                    v[i2] = (by & (1u << i2)) ? (short)0x3F80 : (short)0;
                bq[rf] = v;
            }
#pragma unroll
            for (int nb = 0; nb < 4; nb++) {
                short8_t af = *(const short8_t*)(xf + (nb * 16 + l15) * 72 + ks * 32 + quad * 8);
#pragma unroll
                for (int rf = 0; rf < 4; rf++)
                    acc[rf][nb] = __builtin_amdgcn_mfma_f32_16x16x32_bf16(af, bq[rf], acc[rf][nb], 0, 0, 0);
            }
        }
    }
    __syncthreads();

    u32* dump = pool;
#pragma unroll
    for (int rf = 0; rf < 4; rf++) {
        int rn = w * 64 + rf * 16 + l15;
        float di = poolf[15104 + rn];
#pragma unroll
        for (int nb = 0; nb < 4; nb++) {
            u32 lo = (u32)f2bf(acc[rf][nb][0] * di) | ((u32)f2bf(acc[rf][nb][1] * di) << 16);
            u32 hi = (u32)f2bf(acc[rf][nb][2] * di) | ((u32)f2bf(acc[rf][nb][3] * di) << 16);
            u32* dst = dump + rn * 36 + nb * 8 + quad * 2;
            dst[0] = lo; dst[1] = hi;
        }
    }
    __syncthreads();
    f32x4 xacc[4][4];
#pragma unroll
    for (int ob = 0; ob < 4; ob++)
#pragma unroll
        for (int rf = 0; rf < 4; rf++)
#pragma unroll
            for (int r = 0; r < 4; r++) xacc[ob][rf][r] = 0.0f;
#pragma unroll
    for (int ks2 = 0; ks2 < 2; ks2++) {
        short8_t b2f[4];
#pragma unroll
        for (int rf = 0; rf < 4; rf++)
            b2f[rf] = *(const short8_t*)((const unsigned short*)dump +
                        (w * 64 + rf * 16 + l15) * 72 + ks2 * 32 + quad * 8);
#pragma unroll
        for (int ob = 0; ob < 4; ob++) {
            short8_t a2 = *(const short8_t*)(W2B + (ob * 16 + l15) * 72 + ks2 * 32 + quad * 8);
#pragma unroll
            for (int rf = 0; rf < 4; rf++)
                xacc[ob][rf] = __builtin_amdgcn_mfma_f32_16x16x32_bf16(a2, b2f[rf], xacc[ob][rf], 0, 0, 0);
        }
    }
#pragma unroll
    for (int ob = 0; ob < 4; ob++) {
#pragma unroll
        for (int r = 0; r < 4; r++) {
            int o = ob * 16 + quad * 4 + r;
            float bb = poolf[15360 + o];
            float s = 0.0f;
#pragma unroll
            for (int rf = 0; rf < 4; rf++) s += fmaxf(xacc[ob][rf][r] + bb, 0.0f);
            s += __shfl_down(s, 8, 16);
            s += __shfl_down(s, 4, 16);
            s += __shfl_down(s, 2, 16);
            s += __shfl_down(s, 1, 16);
            if (l15 == 0) atomicAdd(&gsum[bt * 64 + o], s);
        }
    }
}

// K4 v5: gi-precompute via MFMA (bf16x3, f32-grade); serial Whh matvec via packed
// f16 v_dot2 (1 readlane+1 dot2 per 2 MACs, halves issue); gates on 2 waves only.
__global__ __launch_bounds__(768, 1) void k4_all(const void* __restrict__ pts,
                                                 const void* __restrict__ Wg,
                                                 const void* __restrict__ bg,
                                                 const void* __restrict__ Wih,
                                                 const void* __restrict__ Whh,
                                                 const void* __restrict__ bih,
                                                 const void* __restrict__ bhh,
                                                 const void* __restrict__ Wf,
                                                 const void* __restrict__ bf_,
                                                 const float* __restrict__ gsum,
                                                 float* __restrict__ out) {
    int b = blockIdx.x, tid = threadIdx.x;
    __shared__ float s_gir[4096];      // [t][c]
    __shared__ float s_giz[4096];
    __shared__ float s_gin[4096];
    __shared__ float sWgT[64 * 65];
    __shared__ float s_gm[2048];
    __shared__ float s_x[2048];
    __shared__ float s_pt[768];        // [slot(6)][c(128)]
    __shared__ unsigned short s_hp[128];  // h as f16
    __shared__ int s_flag;
    bool bf = detect_bf16(pts, tid, &s_flag);
    int lane = tid & 63, wv = tid >> 6;
    int l15 = lane & 15, quad = lane >> 4;
    int hi = (tid >= 384) ? 1 : 0;      // wave-uniform
    int r = tid - hi * 384;             // 0..383

    for (int idx = tid; idx < 4096; idx += 768) {
        int o = idx >> 6, k = idx & 63;
        sWgT[k * 65 + o] = ldf(Wg, idx, bf);
    }
    for (int idx = tid; idx < 2048; idx += 768)
        s_gm[idx] = gsum[(size_t)b * 2048 + idx] * (1.0f / 1024.0f);
    __syncthreads();
    // phase A: x[t][c] = bg[c] + Wg[c,:] @ gm[t,:]  (f32 VALU, small)
    for (int idx = tid; idx < 2048; idx += 768) {
        int t = idx >> 6, c = idx & 63;
        float s0 = ldf(bg, c, bf), s1 = 0.f, s2 = 0.f, s3 = 0.f;
        const float* gm = s_gm + t * 64;
#pragma unroll
        for (int k = 0; k < 64; k += 4) {
            s0 = fmaf(sWgT[k * 65 + c],       gm[k],     s0);
            s1 = fmaf(sWgT[(k + 1) * 65 + c], gm[k + 1], s1);
            s2 = fmaf(sWgT[(k + 2) * 65 + c], gm[k + 2], s2);
            s3 = fmaf(sWgT[(k + 3) * 65 + c], gm[k + 3], s3);
        }
        s_x[idx] = (s0 + s1) + (s2 + s3);
    }
    // Whh half-row as 32 f16 pairs in VGPRs (overlaps with phase A latency)
    u32 whp[32];
    {
        int koff = r * 128 + hi * 64;
        if (bf) {
            const u32* wp = (const u32*)Whh + koff / 2;
#pragma unroll
            for (int m = 0; m < 32; m++) {
                u32 wq = wp[m];
                whp[m] = pkh(bfi(wq & 0xFFFFu), bfi(wq >> 16));
            }
        } else {
            const float2* wp = (const float2*)Whh + koff / 2;
#pragma unroll
            for (int m = 0; m < 32; m++) {
                float2 v = wp[m];
                whp[m] = pkh(v.x, v.y);
            }
        }
    }
    float bhr = hi ? 0.0f : ldf(bhh, r, bf);
    __syncthreads();   // s_x ready

    // gi = X @ Wih^T + bih via MFMA (bf16x3). Wave wv owns nt = 2wv, 2wv+1.
    {
        short8_t Ah[2][2], Al[2][2];   // [mt][ks]
#pragma unroll
        for (int mt = 0; mt < 2; mt++)
#pragma unroll
            for (int ks = 0; ks < 2; ks++) {
                const float* xs = s_x + (mt * 16 + l15) * 64 + ks * 32 + quad * 8;
                short8_t ah, al;
#pragma unroll
                for (int i = 0; i < 8; i++) {
                    float v = xs[i];
                    unsigned short hb = f2bf(v);
                    ah[i] = (short)hb;
                    al[i] = (short)f2bf(v - bfi(hb));
                }
                Ah[mt][ks] = ah; Al[mt][ks] = al;
            }
#pragma unroll
        for (int ni = 0; ni < 2; ni++) {
            int nt = wv * 2 + ni;
            int c = nt * 16 + l15;
            float bv = ldf(bih, c, bf);
            short8_t Bh[2], Bl[2];
#pragma unroll
            for (int ks = 0; ks < 2; ks++) {
                int base = c * 64 + ks * 32 + quad * 8;
                short8_t bh, bl;
#pragma unroll
                for (int i = 0; i < 8; i++) {
                    float v = ldf(Wih, base + i, bf);
                    unsigned short hb = f2bf(v);
                    bh[i] = (short)hb;
                    bl[i] = (short)f2bf(v - bfi(hb));
                }
                Bh[ks] = bh; Bl[ks] = bl;
            }
            float* gdst = ((nt >> 3) == 0) ? s_gir : (((nt >> 3) == 1) ? s_giz : s_gin);
            int cpart = (nt & 7) * 16 + l15;
#pragma unroll
            for (int mt = 0; mt < 2; mt++) {
                f32x4 acc; acc[0] = bv; acc[1] = bv; acc[2] = bv; acc[3] = bv;
#pragma unroll
                for (int ks = 0; ks < 2; ks++) {
                    acc = __builtin_amdgcn_mfma_f32_16x16x32_bf16(Ah[mt][ks], Bh[ks], acc, 0, 0, 0);
                    acc = __builtin_amdgcn_mfma_f32_16x16x32_bf16(Ah[mt][ks], Bl[ks], acc, 0, 0, 0);
                    acc = __builtin_amdgcn_mfma_f32_16x16x32_bf16(Al[mt][ks], Bh[ks], acc, 0, 0, 0);
                }
#pragma unroll
                for (int rr2 = 0; rr2 < 4; rr2++) {
                    int t = mt * 16 + quad * 4 + rr2;
                    gdst[t * 128 + cpart] = acc[rr2];
                }
            }
        }
    }
    int slot = (r >> 7) * 2 + hi;       // gate(of row r)*2 + half
    int cpart = r & 127;
    float h_self = 0.0f, hsum = 0.0f;   // live in tid<128 threads
    u32 hpreg = 0;                      // h==0 at t=0
    __syncthreads();                    // gi ready

    for (int t = 0; t < 32; t++) {
        float s0 = bhr, s1 = 0.f, s2 = 0.f, s3 = 0.f;
#pragma unroll
        for (int m = 0; m < 32; m += 4) {
            s0 = fdot2h(whp[m],     rdlaneu(hpreg, m),     s0);
            s1 = fdot2h(whp[m + 1], rdlaneu(hpreg, m + 1), s1);
            s2 = fdot2h(whp[m + 2], rdlaneu(hpreg, m + 2), s2);
            s3 = fdot2h(whp[m + 3], rdlaneu(hpreg, m + 3), s3);
        }
        s_pt[slot * 128 + cpart] = (s0 + s1) + (s2 + s3);
        __syncthreads();
        if (tid < 128) {
            int c = tid;
            float gr = s_gir[t * 128 + c] + s_pt[c]       + s_pt[128 + c];
            float gz = s_giz[t * 128 + c] + s_pt[256 + c] + s_pt[384 + c];
            float hn = s_pt[512 + c] + s_pt[640 + c];
            float rr = sigm(gr);
            float zz = sigm(gz);
            float n  = tanh_f(fmaf(rr, hn, s_gin[t * 128 + c]));
            float hnew = fmaf(zz, h_self - n, n);
            h_self = hnew; hsum += hnew;
            s_hp[c] = f16b(hnew);
        }
        __syncthreads();
        hpreg = ((const u32*)s_hp)[hi * 32 + (lane & 31)];
    }
    if (tid < 128) s_gm[tid] = hsum;
    __syncthreads();
    if (tid < 128) {
        float hm = s_gm[tid] * (1.0f / 32.0f);
        s_gm[256 + tid] = ldf(Wf, tid, bf) * hm;
        s_gm[384 + tid] = ldf(Wf, 128 + tid, bf) * hm;
    }
    __syncthreads();
    if (tid < 2) {
        float s = ldf(bf_, tid, bf);
        for (int k = 0; k < 128; k++) s += s_gm[256 + tid * 128 + k];
        out[b * 2 + tid] = s;   // f32 output (verified R4)
    }
}

extern "C" void kernel_launch(void* const* d_in, const int* in_sizes, int n_in,
                              void* d_out, int out_size, void* d_ws, size_t ws_size,
                              hipStream_t stream) {
    const void* pts = d_in[0];
    const void* W1  = d_in[1];
    const void* b1  = d_in[2];
    const void* W2  = d_in[3];
    const void* b2  = d_in[4];
    const void* Wg  = d_in[5];
    const void* bg  = d_in[6];
    const void* Wih = d_in[7];
    const void* Whh = d_in[8];
    const void* bih = d_in[9];
    const void* bhh = d_in[10];
    const void* Wf  = d_in[11];
    const void* bf_ = d_in[12];

    // ws: dinv 512K | gsum 32K | bm 16M | x1vB 18M  (~34.5 MB)
    float* dinv = (float*)d_ws;
    float* gsum = dinv + (size_t)BT * N_PTS;
    u32*   bm   = (u32*)(gsum + BT * 64);
    u32*   x1vB = bm + (size_t)BT * 32768;

    k1_bm  <<<512, 256, 0, stream>>>(pts, dinv, gsum, bm);
    k3a_x1v<<<512, 256, 0, stream>>>(pts, W1, b1, dinv, bm, x1vB);
    k3_mfma<<<512, 256, 0, stream>>>(pts, W2, b2, dinv, bm, x1vB, gsum);
    k4_all <<<4, 768, 0, stream>>>(pts, Wg, bg, Wih, Whh, bih, bhh, Wf, bf_,
                                   gsum, (float*)d_out);
}